// Round 12
// baseline (174.447 us; speedup 1.0000x reference)
//
#include <hip/hip_runtime.h>
#include <stdint.h>

#define DM 1024
#define HEADS 16
#define DH 64
#define BQ 4
#define TT 2048
#define MTOT (BQ*TT)  // 8192
#define NQT (TT/64)   // 32 q-tiles per (b,h)

typedef __attribute__((ext_vector_type(8))) __bf16 bf16x8;
typedef __attribute__((ext_vector_type(4))) float f32x4;
typedef __attribute__((ext_vector_type(4))) uint32_t u32x4;
typedef unsigned short u16;
typedef __attribute__((ext_vector_type(8))) unsigned short u16x8;

__device__ __forceinline__ u16 f2b(float f) {
  uint32_t u = __builtin_bit_cast(uint32_t, f);
  u = (u + 0x7fffu + ((u >> 16) & 1u)) >> 16;
  return (u16)u;
}

__device__ __forceinline__ uint32_t cvtpk(float lo, float hi) {
  uint32_t r;
  asm("v_cvt_pk_bf16_f32 %0, %1, %2" : "=v"(r) : "v"(lo), "v"(hi));
  return r;
}

__device__ __forceinline__ void gload_lds16(const u16* g, u16* l) {
  __builtin_amdgcn_global_load_lds(
      (const __attribute__((address_space(1))) void*)g,
      (__attribute__((address_space(3))) void*)l, 16, 0, 0);
}

// ---------------- fused cast: x, Wq|Wk|Wv (contiguous), Wo -> bf16 ----------------
#define NX (MTOT * DM / 4)   // float4s in x
#define NW (DM * DM / 4)     // float4s per weight matrix
__global__ __launch_bounds__(256) void cast_all(const float* __restrict__ x,
                                                const float* __restrict__ Wq,
                                                const float* __restrict__ Wk,
                                                const float* __restrict__ Wv,
                                                const float* __restrict__ Wo,
                                                u16* __restrict__ xb,
                                                u16* __restrict__ wqkvb,
                                                u16* __restrict__ wob) {
  int i = blockIdx.x * 256 + threadIdx.x;
  const float* src; u16* dst;
  if (i < NX)               { src = x;  dst = xb; }
  else if (i < NX + NW)     { src = Wq; dst = wqkvb;          i -= NX; }
  else if (i < NX + 2 * NW) { src = Wk; dst = wqkvb + 4 * NW; i -= NX + NW; }
  else if (i < NX + 3 * NW) { src = Wv; dst = wqkvb + 8 * NW; i -= NX + 2 * NW; }
  else                      { src = Wo; dst = wob;            i -= NX + 3 * NW; }
  float4 v = ((const float4*)src)[i];
  ushort4 o;
  o.x = f2b(v.x); o.y = f2b(v.y); o.z = f2b(v.z); o.w = f2b(v.w);
  ((ushort4*)dst)[i] = o;
}

// ---------------- fused QKV GEMM, 256x256, counted-vmcnt + 2-phase interleave --
// (unchanged from round 11)
#define BKq 32
#define NKq (DM / BKq)          // 32 K-tiles
#define SLOT_A (256 * BKq)      // 8192 elems (16KB)
#define SLOT_E (2 * SLOT_A)     // 16384 elems (32KB) per slot

__global__ __launch_bounds__(512, 2) void gemm_qkv8(const u16* __restrict__ A,
                                                    const u16* __restrict__ W,
                                                    const float* __restrict__ bq,
                                                    const float* __restrict__ bk,
                                                    const float* __restrict__ bv,
                                                    u16* __restrict__ Qo,
                                                    u16* __restrict__ Ko,
                                                    u16* __restrict__ Vto,
                                                    float qs) {
  __shared__ u16 lds[4 * SLOT_E];  // 128 KB
  const int tid = threadIdx.x, lane = tid & 63, wave = tid >> 6;
  const int fr = lane & 15, g = lane >> 4;
  const int wm = wave >> 2, wn = wave & 3;

  int bid = blockIdx.x;
  bid = (bid & 7) * 48 + (bid >> 3);
  const int bx = bid % 12, by = bid / 12;
  const int m0 = by * 256, n0 = bx * 256;

  const int srow = tid >> 2;
  const int schunk = (tid & 3) ^ ((tid >> 3) & 3);
  const u16* gA0 = A + (size_t)(m0 + srow) * DM + schunk * 8;
  const u16* gA1 = gA0 + (size_t)128 * DM;
  const u16* gB0 = W + (size_t)(n0 + srow) * DM + schunk * 8;
  const u16* gB1 = gB0 + (size_t)128 * DM;
  const int dA0 = wave * 512;
  const int dA1 = 4096 + wave * 512;
  const int dB0 = SLOT_A + wave * 512;
  const int dB1 = SLOT_A + 4096 + wave * 512;

#define STAGE_Ah(slot, kt) {                                 \
    u16* ls = &lds[(slot) * SLOT_E];                         \
    const int ke = (kt) * BKq;                               \
    gload_lds16(gA0 + ke, ls + dA0);                         \
    gload_lds16(gA1 + ke, ls + dA1); }
#define STAGE_Bh(slot, kt) {                                 \
    u16* ls = &lds[(slot) * SLOT_E];                         \
    const int ke = (kt) * BKq;                               \
    gload_lds16(gB0 + ke, ls + dB0);                         \
    gload_lds16(gB1 + ke, ls + dB1); }

  const int rchunk = (g ^ ((fr >> 1) & 3)) * 8;
  const int offA = (wm * 128 + fr) * 32 + rchunk;
  const int offB = SLOT_A + (wn * 64 + fr) * 32 + rchunk;

  f32x4 acc[8][4];
#pragma unroll
  for (int mi = 0; mi < 8; ++mi)
#pragma unroll
    for (int ni = 0; ni < 4; ++ni) acc[mi][ni] = (f32x4){0.f, 0.f, 0.f, 0.f};

  bf16x8 afA[8], bfA[4], afB[8], bfB[4];

#define READ_P1(AFv, BFv, kt) {                              \
    const u16* sl = &lds[((kt) & 3) * SLOT_E];               \
    _Pragma("unroll")                                        \
    for (int mi = 0; mi < 4; ++mi)                           \
      AFv[mi] = *(const bf16x8*)&sl[offA + mi * 512];        \
    _Pragma("unroll")                                        \
    for (int ni = 0; ni < 4; ++ni)                           \
      BFv[ni] = *(const bf16x8*)&sl[offB + ni * 512]; }
#define READ_P2(AFv, kt) {                                   \
    const u16* sl = &lds[((kt) & 3) * SLOT_E];               \
    _Pragma("unroll")                                        \
    for (int mi = 4; mi < 8; ++mi)                           \
      AFv[mi] = *(const bf16x8*)&sl[offA + mi * 512]; }

#define MFMA_P1(AFv, BFv) {                                  \
    __builtin_amdgcn_s_setprio(1);                           \
    _Pragma("unroll")                                        \
    for (int mi = 0; mi < 4; ++mi)                           \
      _Pragma("unroll")                                      \
      for (int ni = 0; ni < 4; ++ni)                         \
        acc[mi][ni] = __builtin_amdgcn_mfma_f32_16x16x32_bf16(AFv[mi], BFv[ni], acc[mi][ni], 0, 0, 0); \
    __builtin_amdgcn_s_setprio(0); }
#define MFMA_P2(AFv, BFv) {                                  \
    __builtin_amdgcn_s_setprio(1);                           \
    _Pragma("unroll")                                        \
    for (int mi = 4; mi < 8; ++mi)                           \
      _Pragma("unroll")                                      \
      for (int ni = 0; ni < 4; ++ni)                         \
        acc[mi][ni] = __builtin_amdgcn_mfma_f32_16x16x32_bf16(AFv[mi], BFv[ni], acc[mi][ni], 0, 0, 0); \
    __builtin_amdgcn_s_setprio(0); }

#define BARQ asm volatile("s_barrier" ::: "memory");
#define WAIT4 asm volatile("s_waitcnt vmcnt(4)" ::: "memory"); BARQ
#define WAIT0 asm volatile("s_waitcnt vmcnt(0)" ::: "memory"); BARQ

#define STEP(AFc, BFc, AFn, BFn, kt, DO_STAGE) {             \
    WAIT4                                                    \
    READ_P1(AFn, BFn, (kt) + 1)                              \
    MFMA_P1(AFc, BFc)                                        \
    if (DO_STAGE) STAGE_Ah(((kt) + 3) & 3, (kt) + 3)         \
    BARQ                                                     \
    READ_P2(AFn, (kt) + 1)                                   \
    MFMA_P2(AFc, BFc)                                        \
    if (DO_STAGE) STAGE_Bh(((kt) + 3) & 3, (kt) + 3) }

  STAGE_Ah(0, 0) STAGE_Bh(0, 0)
  STAGE_Ah(1, 1) STAGE_Bh(1, 1)
  STAGE_Ah(2, 2) STAGE_Bh(2, 2)
  asm volatile("s_waitcnt vmcnt(8)" ::: "memory");
  asm volatile("s_barrier" ::: "memory");
  READ_P1(afA, bfA, 0)
  READ_P2(afA, 0)

  for (int kt = 0; kt < NKq - 4; kt += 2) {
    STEP(afA, bfA, afB, bfB, kt, true)
    STEP(afB, bfB, afA, bfA, kt + 1, true)
  }
  STEP(afA, bfA, afB, bfB, NKq - 4, true)
  STEP(afB, bfB, afA, bfA, NKq - 3, false)
  WAIT0
  READ_P1(afB, bfB, NKq - 1)
  MFMA_P1(afA, bfA)
  BARQ
  READ_P2(afB, NKq - 1)
  MFMA_P2(afA, bfA)
  MFMA_P1(afB, bfB)
  MFMA_P2(afB, bfB)

  const int g4 = g * 4;
  const int seg = n0 >> 10;
  const int nbase = (n0 & 1023) + wn * 64 + fr;
  if (seg == 0) {
#pragma unroll
    for (int ni = 0; ni < 4; ++ni) {
      const int cgl = nbase + ni * 16;
      const float bb = bq[cgl];
      const int hh = cgl >> 6, d = cgl & 63;
#pragma unroll
      for (int mi = 0; mi < 8; ++mi) {
        const int m = m0 + wm * 128 + mi * 16 + g4;
        const int bi = m >> 11, t = m & 2047;
        u16* dst = &Qo[(((size_t)bi * HEADS + hh) * TT + t) * DH + d];
#pragma unroll
        for (int j = 0; j < 4; ++j)
          dst[(size_t)j * DH] = f2b((acc[mi][ni][j] + bb) * qs);
      }
    }
  } else if (seg == 1) {
#pragma unroll
    for (int ni = 0; ni < 4; ++ni) {
      const int cgl = nbase + ni * 16;
      const float bb = bk[cgl];
      const int hh = cgl >> 6, d = cgl & 63;
#pragma unroll
      for (int mi = 0; mi < 8; ++mi) {
        const int m = m0 + wm * 128 + mi * 16 + g4;
        const int bi = m >> 11, t = m & 2047;
        u16* dst = &Ko[(((size_t)bi * HEADS + hh) * TT + t) * DH + d];
#pragma unroll
        for (int j = 0; j < 4; ++j)
          dst[(size_t)j * DH] = f2b(acc[mi][ni][j] + bb);
      }
    }
  } else {
#pragma unroll
    for (int ni = 0; ni < 4; ++ni) {
      const int cgl = nbase + ni * 16;
      const float bb = bv[cgl];
      const int hh = cgl >> 6, d = cgl & 63;
#pragma unroll
      for (int mi = 0; mi < 8; ++mi) {
        const int t0 = (m0 + wm * 128 + mi * 16 + g4) & 2047;
        const int bi = (m0 + wm * 128 + mi * 16 + g4) >> 11;
        const int w64 = t0 & 63;
        const int pos = (t0 & ~63) | (((w64 >> 5) & 1) << 5) | (((w64 >> 2) & 3) << 3) |
                        (((w64 >> 4) & 1) << 2);
        ushort4 o;
        o.x = f2b(acc[mi][ni][0] + bb);
        o.y = f2b(acc[mi][ni][1] + bb);
        o.z = f2b(acc[mi][ni][2] + bb);
        o.w = f2b(acc[mi][ni][3] + bb);
        *(ushort4*)&Vto[(((size_t)bi * HEADS + hh) * DH + d) * TT + pos] = o;
      }
    }
  }
#undef STAGE_Ah
#undef STAGE_Bh
#undef READ_P1
#undef READ_P2
#undef MFMA_P1
#undef MFMA_P2
#undef STEP
#undef BARQ
#undef WAIT4
#undef WAIT0
}

// ---------------- O-projection GEMM (unchanged from round 11) ----------------
#define SLOT_OA (256 * 32)
#define SLOT_OB (128 * 32)
#define SLOT_OE (SLOT_OA + SLOT_OB)

__global__ __launch_bounds__(512, 2) void gemm_out8(const u16* __restrict__ A,
                                                    const u16* __restrict__ Bw,
                                                    const float* __restrict__ bias,
                                                    float* __restrict__ outp) {
  __shared__ u16 lds[4 * SLOT_OE];  // 96 KB
  const int tid = threadIdx.x, lane = tid & 63, wave = tid >> 6;
  const int fr = lane & 15, g = lane >> 4;
  const int wm = wave >> 1, wn = wave & 1;

  const int bx = blockIdx.x >> 5, by = blockIdx.x & 31;
  const int m0 = by * 256, n0 = bx * 128;

  const int srow = tid >> 2;
  const int schunk = (tid & 3) ^ ((tid >> 3) & 3);
  const u16* gA0 = A + (size_t)(m0 + srow) * DM + schunk * 8;
  const u16* gA1 = gA0 + (size_t)128 * DM;
  const u16* gB0 = Bw + (size_t)(n0 + srow) * DM + schunk * 8;
  const int dA0 = wave * 512;
  const int dA1 = 4096 + wave * 512;
  const int dB0 = SLOT_OA + wave * 512;

#define STAGEO(slot, kt) {                                   \
    u16* ls = &lds[(slot) * SLOT_OE];                        \
    const int ke = (kt) * 32;                                \
    gload_lds16(gA0 + ke, ls + dA0);                         \
    gload_lds16(gA1 + ke, ls + dA1);                         \
    gload_lds16(gB0 + ke, ls + dB0); }

  const int rchunk = (g ^ ((fr >> 1) & 3)) * 8;
  const int offA = (wm * 64 + fr) * 32 + rchunk;
  const int offB = SLOT_OA + (wn * 64 + fr) * 32 + rchunk;

  f32x4 acc[4][4];
#pragma unroll
  for (int mi = 0; mi < 4; ++mi)
#pragma unroll
    for (int ni = 0; ni < 4; ++ni) acc[mi][ni] = (f32x4){0.f, 0.f, 0.f, 0.f};

  bf16x8 afA[4], bfA[4], afB[4], bfB[4];

#define READO(AFv, BFv, kt) {                                \
    const u16* sl = &lds[((kt) & 3) * SLOT_OE];              \
    _Pragma("unroll")                                        \
    for (int mi = 0; mi < 4; ++mi)                           \
      AFv[mi] = *(const bf16x8*)&sl[offA + mi * 512];        \
    _Pragma("unroll")                                        \
    for (int ni = 0; ni < 4; ++ni)                           \
      BFv[ni] = *(const bf16x8*)&sl[offB + ni * 512]; }

#define MFMAO(AFv, BFv) {                                    \
    __builtin_amdgcn_s_setprio(1);                           \
    _Pragma("unroll")                                        \
    for (int mi = 0; mi < 4; ++mi)                           \
      _Pragma("unroll")                                      \
      for (int ni = 0; ni < 4; ++ni)                         \
        acc[mi][ni] = __builtin_amdgcn_mfma_f32_16x16x32_bf16(AFv[mi], BFv[ni], acc[mi][ni], 0, 0, 0); \
    __builtin_amdgcn_s_setprio(0); }

#define OW3 asm volatile("s_waitcnt vmcnt(3)" ::: "memory"); \
            asm volatile("s_barrier" ::: "memory");
#define OW0 asm volatile("s_waitcnt vmcnt(0)" ::: "memory"); \
            asm volatile("s_barrier" ::: "memory");

  STAGEO(0, 0)
  STAGEO(1, 1)
  STAGEO(2, 2)
  asm volatile("s_waitcnt vmcnt(6)" ::: "memory");
  asm volatile("s_barrier" ::: "memory");
  READO(afA, bfA, 0)

  for (int kt = 0; kt < 28; kt += 2) {
    OW3
    READO(afB, bfB, kt + 1)
    MFMAO(afA, bfA)
    STAGEO((kt + 3) & 3, kt + 3)
    OW3
    READO(afA, bfA, kt + 2)
    MFMAO(afB, bfB)
    STAGEO((kt + 4) & 3, kt + 4)
  }
  OW3
  READO(afB, bfB, 29)
  MFMAO(afA, bfA)
  STAGEO(3, 31)
  OW3
  READO(afA, bfA, 30)
  MFMAO(afB, bfB)
  OW0
  READO(afB, bfB, 31)
  MFMAO(afA, bfA)
  MFMAO(afB, bfB)

  const int g4 = g * 4;
#pragma unroll
  for (int mi = 0; mi < 4; ++mi) {
    const int rg = m0 + wm * 64 + mi * 16 + g4;
#pragma unroll
    for (int ni = 0; ni < 4; ++ni) {
      const int cg = n0 + wn * 64 + ni * 16 + fr;
      const float bb = bias[cg];
#pragma unroll
      for (int j = 0; j < 4; ++j)
        outp[(size_t)(rg + j) * DM + cg] = acc[mi][ni][j] + bb;
    }
  }
#undef STAGEO
#undef READO
#undef MFMAO
#undef OW3
#undef OW0
}

// ---------------- flash attention, causal, PASS-MERGED ----------------
// XCD-local decode (round 9) + XOR-swizzled LDS (round 10).  NEW: the block's
// two q-tiles {qtA=31-pj, qtB=pj} share one kvb loop.  qtB < qtA always, so
// pass B's KV range is a prefix: loop 1 (kvb <= qtB) computes BOTH q-tiles
// from one staged tile, reading each K/V fragment ONCE for two MFMAs; loop 2
// (qtB < kvb <= qtA) is A-only.  Stages/barriers drop 33 -> 32-pj (avg -26%).
__global__ __launch_bounds__(256) void attn_fwd(const u16* __restrict__ Q,
                                                const u16* __restrict__ K,
                                                const u16* __restrict__ Vt,
                                                u16* __restrict__ O) {
  const int o_ = blockIdx.x;
  const int r_ = o_ & 7, q_ = o_ >> 3;
  const int gidx = r_ * 8 + (q_ >> 4);     // (b,h) group 0..63
  const int pj = q_ & 15;
  const int b = gidx >> 4, h = gidx & 15;
  const int tid = threadIdx.x, lane = tid & 63, wave = tid >> 6;
  __shared__ u16 Ks[64 * 64];
  __shared__ u16 Vs[64 * 64];

  const size_t bh = ((size_t)b * HEADS + h) * TT;
  const size_t vbse = ((size_t)b * HEADS + h) * DH;
  const int fr = lane & 15, g = lane >> 4;
  const int sr = tid >> 2;
  const int sc0 = tid & 3;

  const int sw1 = (sc0 ^ (sr & 7)) * 8;
  const int sw2 = ((sc0 + 4) ^ (sr & 7)) * 8;
  const int sgc = sc0 * 8;
  const int rk0 = (g ^ (fr & 7)) * 8;
  const int rk1 = ((4 + g) ^ (fr & 7)) * 8;
  const int k8 = g * 8;

  const int qtA = NQT - 1 - pj, qtB = pj;
  const int qrowA = qtA * 64 + wave * 16 + fr;
  const int qrowB = qtB * 64 + wave * 16 + fr;
  const bf16x8 qfA0 = *(const bf16x8*)&Q[(bh + qrowA) * DH + k8];
  const bf16x8 qfA1 = *(const bf16x8*)&Q[(bh + qrowA) * DH + 32 + k8];
  const bf16x8 qfB0 = *(const bf16x8*)&Q[(bh + qrowB) * DH + k8];
  const bf16x8 qfB1 = *(const bf16x8*)&Q[(bh + qrowB) * DH + 32 + k8];

  float lsumA = 0.f, lsumB = 0.f;
  f32x4 oaccA[4], oaccB[4];
#pragma unroll
  for (int c = 0; c < 4; ++c) {
    oaccA[c] = (f32x4){0.f, 0.f, 0.f, 0.f};
    oaccB[c] = (f32x4){0.f, 0.f, 0.f, 0.f};
  }

#define STAGE_KV(kv0) {                                          \
    const u16* kg = &K[(bh + (kv0) + sr) * DH + sgc];            \
    u16x8 ka = *(const u16x8*)kg;                                \
    u16x8 kc = *(const u16x8*)(kg + 32);                         \
    const u16* vg = &Vt[(vbse + sr) * TT + (kv0) + sgc];         \
    u16x8 va = *(const u16x8*)vg;                                \
    u16x8 vc = *(const u16x8*)(vg + 32);                         \
    *(u16x8*)&Ks[sr * 64 + sw1] = ka;                            \
    *(u16x8*)&Ks[sr * 64 + sw2] = kc;                            \
    *(u16x8*)&Vs[sr * 64 + sw1] = va;                            \
    *(u16x8*)&Vs[sr * 64 + sw2] = vc;                            \
  }

  // ---- loop 1: shared region, both q-tiles per staged tile ----
  for (int kvb = 0; kvb <= qtB; ++kvb) {
    const int kv0 = kvb * 64;
    STAGE_KV(kv0)
    __syncthreads();

    f32x4 sA[4], sB[4];
    __builtin_amdgcn_s_setprio(1);
#pragma unroll
    for (int c = 0; c < 4; ++c) {
      bf16x8 kb0 = *(const bf16x8*)&Ks[(c * 16 + fr) * 64 + rk0];
      bf16x8 kb1 = *(const bf16x8*)&Ks[(c * 16 + fr) * 64 + rk1];
      f32x4 tA = (f32x4){0.f, 0.f, 0.f, 0.f};
      tA = __builtin_amdgcn_mfma_f32_16x16x32_bf16(kb0, qfA0, tA, 0, 0, 0);
      tA = __builtin_amdgcn_mfma_f32_16x16x32_bf16(kb1, qfA1, tA, 0, 0, 0);
      sA[c] = tA;
      f32x4 tB = (f32x4){0.f, 0.f, 0.f, 0.f};
      tB = __builtin_amdgcn_mfma_f32_16x16x32_bf16(kb0, qfB0, tB, 0, 0, 0);
      tB = __builtin_amdgcn_mfma_f32_16x16x32_bf16(kb1, qfB1, tB, 0, 0, 0);
      sB[c] = tB;
    }
    __builtin_amdgcn_s_setprio(0);

    if (kvb == qtB) {  // B's diagonal tile (A never masked here: kvb <= qtB < qtA)
#pragma unroll
      for (int c = 0; c < 4; ++c) {
        const int colg = kv0 + c * 16 + 4 * g;
#pragma unroll
        for (int r = 0; r < 4; ++r)
          if (colg + r > qrowB) sB[c][r] = -1e30f;
      }
    }

    float rsA = 0.f, rsB = 0.f;
    uint32_t pkA[8], pkB[8];
#pragma unroll
    for (int c = 0; c < 4; ++c) {
      float a0 = __builtin_amdgcn_exp2f(sA[c][0]);
      float a1 = __builtin_amdgcn_exp2f(sA[c][1]);
      float a2 = __builtin_amdgcn_exp2f(sA[c][2]);
      float a3 = __builtin_amdgcn_exp2f(sA[c][3]);
      rsA += (a0 + a1) + (a2 + a3);
      pkA[2 * c] = cvtpk(a0, a1);
      pkA[2 * c + 1] = cvtpk(a2, a3);
      float b0 = __builtin_amdgcn_exp2f(sB[c][0]);
      float b1 = __builtin_amdgcn_exp2f(sB[c][1]);
      float b2 = __builtin_amdgcn_exp2f(sB[c][2]);
      float b3 = __builtin_amdgcn_exp2f(sB[c][3]);
      rsB += (b0 + b1) + (b2 + b3);
      pkB[2 * c] = cvtpk(b0, b1);
      pkB[2 * c + 1] = cvtpk(b2, b3);
    }
    rsA += __shfl_xor(rsA, 16);
    rsA += __shfl_xor(rsA, 32);
    lsumA += rsA;
    rsB += __shfl_xor(rsB, 16);
    rsB += __shfl_xor(rsB, 32);
    lsumB += rsB;

    const bf16x8 paA0 = __builtin_bit_cast(bf16x8, (u32x4){pkA[0], pkA[1], pkA[2], pkA[3]});
    const bf16x8 paA1 = __builtin_bit_cast(bf16x8, (u32x4){pkA[4], pkA[5], pkA[6], pkA[7]});
    const bf16x8 paB0 = __builtin_bit_cast(bf16x8, (u32x4){pkB[0], pkB[1], pkB[2], pkB[3]});
    const bf16x8 paB1 = __builtin_bit_cast(bf16x8, (u32x4){pkB[4], pkB[5], pkB[6], pkB[7]});

    __builtin_amdgcn_s_setprio(1);
#pragma unroll
    for (int c = 0; c < 4; ++c) {
      bf16x8 vb0 = *(const bf16x8*)&Vs[(c * 16 + fr) * 64 + rk0];
      bf16x8 vb1 = *(const bf16x8*)&Vs[(c * 16 + fr) * 64 + rk1];
      oaccA[c] = __builtin_amdgcn_mfma_f32_16x16x32_bf16(vb0, paA0, oaccA[c], 0, 0, 0);
      oaccA[c] = __builtin_amdgcn_mfma_f32_16x16x32_bf16(vb1, paA1, oaccA[c], 0, 0, 0);
      oaccB[c] = __builtin_amdgcn_mfma_f32_16x16x32_bf16(vb0, paB0, oaccB[c], 0, 0, 0);
      oaccB[c] = __builtin_amdgcn_mfma_f32_16x16x32_bf16(vb1, paB1, oaccB[c], 0, 0, 0);
    }
    __builtin_amdgcn_s_setprio(0);
    __syncthreads();
  }

  // ---- loop 2: A-only region ----
  for (int kvb = qtB + 1; kvb <= qtA; ++kvb) {
    const int kv0 = kvb * 64;
    STAGE_KV(kv0)
    __syncthreads();

    f32x4 sA[4];
    __builtin_amdgcn_s_setprio(1);
#pragma unroll
    for (int c = 0; c < 4; ++c) {
      bf16x8 kb0 = *(const bf16x8*)&Ks[(c * 16 + fr) * 64 + rk0];
      bf16x8 kb1 = *(const bf16x8*)&Ks[(c * 16 + fr) * 64 + rk1];
      f32x4 tA = (f32x4){0.f, 0.f, 0.f, 0.f};
      tA = __builtin_amdgcn_mfma_f32_16x16x32_bf16(kb0, qfA0, tA, 0, 0, 0);
      tA = __builtin_amdgcn_mfma_f32_16x16x32_bf16(kb1, qfA1, tA, 0, 0, 0);
      sA[c] = tA;
    }
    __builtin_amdgcn_s_setprio(0);

    if (kvb == qtA) {  // A's diagonal tile
#pragma unroll
      for (int c = 0; c < 4; ++c) {
        const int colg = kv0 + c * 16 + 4 * g;
#pragma unroll
        for (int r = 0; r < 4; ++r)
          if (colg + r > qrowA) sA[c][r] = -1e30f;
      }
    }

    float rsA = 0.f;
    uint32_t pkA[8];
#pragma unroll
    for (int c = 0; c < 4; ++c) {
      float a0 = __builtin_amdgcn_exp2f(sA[c][0]);
      float a1 = __builtin_amdgcn_exp2f(sA[c][1]);
      float a2 = __builtin_amdgcn_exp2f(sA[c][2]);
      float a3 = __builtin_amdgcn_exp2f(sA[c][3]);
      rsA += (a0 + a1) + (a2 + a3);
      pkA[2 * c] = cvtpk(a0, a1);
      pkA[2 * c + 1] = cvtpk(a2, a3);
    }
    rsA += __shfl_xor(rsA, 16);
    rsA += __shfl_xor(rsA, 32);
    lsumA += rsA;

    const bf16x8 paA0 = __builtin_bit_cast(bf16x8, (u32x4){pkA[0], pkA[1], pkA[2], pkA[3]});
    const bf16x8 paA1 = __builtin_bit_cast(bf16x8, (u32x4){pkA[4], pkA[5], pkA[6], pkA[7]});

    __builtin_amdgcn_s_setprio(1);
#pragma unroll
    for (int c = 0; c < 4; ++c) {
      bf16x8 vb0 = *(const bf16x8*)&Vs[(c * 16 + fr) * 64 + rk0];
      bf16x8 vb1 = *(const bf16x8*)&Vs[(c * 16 + fr) * 64 + rk1];
      oaccA[c] = __builtin_amdgcn_mfma_f32_16x16x32_bf16(vb0, paA0, oaccA[c], 0, 0, 0);
      oaccA[c] = __builtin_amdgcn_mfma_f32_16x16x32_bf16(vb1, paA1, oaccA[c], 0, 0, 0);
    }
    __builtin_amdgcn_s_setprio(0);
    __syncthreads();
  }

  // ---- epilogues ----
  const float invA = 1.f / lsumA;
#pragma unroll
  for (int c = 0; c < 4; ++c) {
    ushort4 o;
    o.x = f2b(oaccA[c][0] * invA);
    o.y = f2b(oaccA[c][1] * invA);
    o.z = f2b(oaccA[c][2] * invA);
    o.w = f2b(oaccA[c][3] * invA);
    *(ushort4*)&O[((size_t)b * TT + qrowA) * DM + h * DH + c * 16 + 4 * g] = o;
  }
  const float invB = 1.f / lsumB;
#pragma unroll
  for (int c = 0; c < 4; ++c) {
    ushort4 o;
    o.x = f2b(oaccB[c][0] * invB);
    o.y = f2b(oaccB[c][1] * invB);
    o.z = f2b(oaccB[c][2] * invB);
    o.w = f2b(oaccB[c][3] * invB);
    *(ushort4*)&O[((size_t)b * TT + qrowB) * DM + h * DH + c * 16 + 4 * g] = o;
  }
#undef STAGE_KV
}

extern "C" void kernel_launch(void* const* d_in, const int* in_sizes, int n_in,
                              void* d_out, int out_size, void* d_ws, size_t ws_size,
                              hipStream_t stream) {
  const float* x  = (const float*)d_in[0];
  const float* Wq = (const float*)d_in[1];
  const float* bq = (const float*)d_in[2];
  const float* Wk = (const float*)d_in[3];
  const float* bk = (const float*)d_in[4];
  const float* Wv = (const float*)d_in[5];
  const float* bv = (const float*)d_in[6];
  const float* Wo = (const float*)d_in[7];
  const float* bo = (const float*)d_in[8];

  char* w = (char*)d_ws;
  u16* xb    = (u16*)w; w += (size_t)MTOT * DM * 2;
  u16* Wqkvb = (u16*)w; w += (size_t)3 * DM * DM * 2;
  u16* Wob   = (u16*)w; w += (size_t)DM * DM * 2;
  u16* Qb    = (u16*)w; w += (size_t)MTOT * DM * 2;
  u16* Kb    = (u16*)w; w += (size_t)MTOT * DM * 2;
  u16* Vtb   = (u16*)w; w += (size_t)MTOT * DM * 2;
  u16* AOb   = (u16*)w; w += (size_t)MTOT * DM * 2;

  cast_all<<<(NX + 4 * NW) / 256, 256, 0, stream>>>(x, Wq, Wk, Wv, Wo, xb, Wqkvb, Wob);

  const float qs = 0.125f * 1.44269504f;  // 1/sqrt(64) * log2(e), folded into Q
  gemm_qkv8<<<384, 512, 0, stream>>>(xb, Wqkvb, bq, bk, bv, Qb, Kb, Vtb, qs);

  attn_fwd<<<1024, 256, 0, stream>>>(Qb, Kb, Vtb, AOb);

  gemm_out8<<<256, 512, 0, stream>>>(AOb, Wob, bo, (float*)d_out);
}

// Round 13
// 159.973 us; speedup vs baseline: 1.0905x; 1.0905x over previous
//
#include <hip/hip_runtime.h>
#include <stdint.h>

#define DM 1024
#define HEADS 16
#define DH 64
#define BQ 4
#define TT 2048
#define MTOT (BQ*TT)  // 8192
#define NQT (TT/64)   // 32 q-tiles per (b,h)

typedef __attribute__((ext_vector_type(8))) __bf16 bf16x8;
typedef __attribute__((ext_vector_type(4))) float f32x4;
typedef __attribute__((ext_vector_type(4))) uint32_t u32x4;
typedef unsigned short u16;
typedef __attribute__((ext_vector_type(8))) unsigned short u16x8;

__device__ __forceinline__ u16 f2b(float f) {
  uint32_t u = __builtin_bit_cast(uint32_t, f);
  u = (u + 0x7fffu + ((u >> 16) & 1u)) >> 16;
  return (u16)u;
}

__device__ __forceinline__ uint32_t cvtpk(float lo, float hi) {
  uint32_t r;
  asm("v_cvt_pk_bf16_f32 %0, %1, %2" : "=v"(r) : "v"(lo), "v"(hi));
  return r;
}

__device__ __forceinline__ void gload_lds16(const u16* g, u16* l) {
  __builtin_amdgcn_global_load_lds(
      (const __attribute__((address_space(1))) void*)g,
      (__attribute__((address_space(3))) void*)l, 16, 0, 0);
}

// ---------------- fused cast: x, Wq|Wk|Wv (contiguous), Wo -> bf16 ----------------
#define NX (MTOT * DM / 4)   // float4s in x
#define NW (DM * DM / 4)     // float4s per weight matrix
__global__ __launch_bounds__(256) void cast_all(const float* __restrict__ x,
                                                const float* __restrict__ Wq,
                                                const float* __restrict__ Wk,
                                                const float* __restrict__ Wv,
                                                const float* __restrict__ Wo,
                                                u16* __restrict__ xb,
                                                u16* __restrict__ wqkvb,
                                                u16* __restrict__ wob) {
  int i = blockIdx.x * 256 + threadIdx.x;
  const float* src; u16* dst;
  if (i < NX)               { src = x;  dst = xb; }
  else if (i < NX + NW)     { src = Wq; dst = wqkvb;          i -= NX; }
  else if (i < NX + 2 * NW) { src = Wk; dst = wqkvb + 4 * NW; i -= NX + NW; }
  else if (i < NX + 3 * NW) { src = Wv; dst = wqkvb + 8 * NW; i -= NX + 2 * NW; }
  else                      { src = Wo; dst = wob;            i -= NX + 3 * NW; }
  float4 v = ((const float4*)src)[i];
  ushort4 o;
  o.x = f2b(v.x); o.y = f2b(v.y); o.z = f2b(v.z); o.w = f2b(v.w);
  ((ushort4*)dst)[i] = o;
}

// ---------------- fused QKV GEMM, 256x256, counted-vmcnt + 2-phase interleave --
// (unchanged from round 11)
#define BKq 32
#define NKq (DM / BKq)          // 32 K-tiles
#define SLOT_A (256 * BKq)      // 8192 elems (16KB)
#define SLOT_E (2 * SLOT_A)     // 16384 elems (32KB) per slot

__global__ __launch_bounds__(512, 2) void gemm_qkv8(const u16* __restrict__ A,
                                                    const u16* __restrict__ W,
                                                    const float* __restrict__ bq,
                                                    const float* __restrict__ bk,
                                                    const float* __restrict__ bv,
                                                    u16* __restrict__ Qo,
                                                    u16* __restrict__ Ko,
                                                    u16* __restrict__ Vto,
                                                    float qs) {
  __shared__ u16 lds[4 * SLOT_E];  // 128 KB
  const int tid = threadIdx.x, lane = tid & 63, wave = tid >> 6;
  const int fr = lane & 15, g = lane >> 4;
  const int wm = wave >> 2, wn = wave & 3;

  int bid = blockIdx.x;
  bid = (bid & 7) * 48 + (bid >> 3);
  const int bx = bid % 12, by = bid / 12;
  const int m0 = by * 256, n0 = bx * 256;

  const int srow = tid >> 2;
  const int schunk = (tid & 3) ^ ((tid >> 3) & 3);
  const u16* gA0 = A + (size_t)(m0 + srow) * DM + schunk * 8;
  const u16* gA1 = gA0 + (size_t)128 * DM;
  const u16* gB0 = W + (size_t)(n0 + srow) * DM + schunk * 8;
  const u16* gB1 = gB0 + (size_t)128 * DM;
  const int dA0 = wave * 512;
  const int dA1 = 4096 + wave * 512;
  const int dB0 = SLOT_A + wave * 512;
  const int dB1 = SLOT_A + 4096 + wave * 512;

#define STAGE_Ah(slot, kt) {                                 \
    u16* ls = &lds[(slot) * SLOT_E];                         \
    const int ke = (kt) * BKq;                               \
    gload_lds16(gA0 + ke, ls + dA0);                         \
    gload_lds16(gA1 + ke, ls + dA1); }
#define STAGE_Bh(slot, kt) {                                 \
    u16* ls = &lds[(slot) * SLOT_E];                         \
    const int ke = (kt) * BKq;                               \
    gload_lds16(gB0 + ke, ls + dB0);                         \
    gload_lds16(gB1 + ke, ls + dB1); }

  const int rchunk = (g ^ ((fr >> 1) & 3)) * 8;
  const int offA = (wm * 128 + fr) * 32 + rchunk;
  const int offB = SLOT_A + (wn * 64 + fr) * 32 + rchunk;

  f32x4 acc[8][4];
#pragma unroll
  for (int mi = 0; mi < 8; ++mi)
#pragma unroll
    for (int ni = 0; ni < 4; ++ni) acc[mi][ni] = (f32x4){0.f, 0.f, 0.f, 0.f};

  bf16x8 afA[8], bfA[4], afB[8], bfB[4];

#define READ_P1(AFv, BFv, kt) {                              \
    const u16* sl = &lds[((kt) & 3) * SLOT_E];               \
    _Pragma("unroll")                                        \
    for (int mi = 0; mi < 4; ++mi)                           \
      AFv[mi] = *(const bf16x8*)&sl[offA + mi * 512];        \
    _Pragma("unroll")                                        \
    for (int ni = 0; ni < 4; ++ni)                           \
      BFv[ni] = *(const bf16x8*)&sl[offB + ni * 512]; }
#define READ_P2(AFv, kt) {                                   \
    const u16* sl = &lds[((kt) & 3) * SLOT_E];               \
    _Pragma("unroll")                                        \
    for (int mi = 4; mi < 8; ++mi)                           \
      AFv[mi] = *(const bf16x8*)&sl[offA + mi * 512]; }

#define MFMA_P1(AFv, BFv) {                                  \
    __builtin_amdgcn_s_setprio(1);                           \
    _Pragma("unroll")                                        \
    for (int mi = 0; mi < 4; ++mi)                           \
      _Pragma("unroll")                                      \
      for (int ni = 0; ni < 4; ++ni)                         \
        acc[mi][ni] = __builtin_amdgcn_mfma_f32_16x16x32_bf16(AFv[mi], BFv[ni], acc[mi][ni], 0, 0, 0); \
    __builtin_amdgcn_s_setprio(0); }
#define MFMA_P2(AFv, BFv) {                                  \
    __builtin_amdgcn_s_setprio(1);                           \
    _Pragma("unroll")                                        \
    for (int mi = 4; mi < 8; ++mi)                           \
      _Pragma("unroll")                                      \
      for (int ni = 0; ni < 4; ++ni)                         \
        acc[mi][ni] = __builtin_amdgcn_mfma_f32_16x16x32_bf16(AFv[mi], BFv[ni], acc[mi][ni], 0, 0, 0); \
    __builtin_amdgcn_s_setprio(0); }

#define BARQ asm volatile("s_barrier" ::: "memory");
#define WAIT4 asm volatile("s_waitcnt vmcnt(4)" ::: "memory"); BARQ
#define WAIT0 asm volatile("s_waitcnt vmcnt(0)" ::: "memory"); BARQ

#define STEP(AFc, BFc, AFn, BFn, kt, DO_STAGE) {             \
    WAIT4                                                    \
    READ_P1(AFn, BFn, (kt) + 1)                              \
    MFMA_P1(AFc, BFc)                                        \
    if (DO_STAGE) STAGE_Ah(((kt) + 3) & 3, (kt) + 3)         \
    BARQ                                                     \
    READ_P2(AFn, (kt) + 1)                                   \
    MFMA_P2(AFc, BFc)                                        \
    if (DO_STAGE) STAGE_Bh(((kt) + 3) & 3, (kt) + 3) }

  STAGE_Ah(0, 0) STAGE_Bh(0, 0)
  STAGE_Ah(1, 1) STAGE_Bh(1, 1)
  STAGE_Ah(2, 2) STAGE_Bh(2, 2)
  asm volatile("s_waitcnt vmcnt(8)" ::: "memory");
  asm volatile("s_barrier" ::: "memory");
  READ_P1(afA, bfA, 0)
  READ_P2(afA, 0)

  for (int kt = 0; kt < NKq - 4; kt += 2) {
    STEP(afA, bfA, afB, bfB, kt, true)
    STEP(afB, bfB, afA, bfA, kt + 1, true)
  }
  STEP(afA, bfA, afB, bfB, NKq - 4, true)
  STEP(afB, bfB, afA, bfA, NKq - 3, false)
  WAIT0
  READ_P1(afB, bfB, NKq - 1)
  MFMA_P1(afA, bfA)
  BARQ
  READ_P2(afB, NKq - 1)
  MFMA_P2(afA, bfA)
  MFMA_P1(afB, bfB)
  MFMA_P2(afB, bfB)

  const int g4 = g * 4;
  const int seg = n0 >> 10;
  const int nbase = (n0 & 1023) + wn * 64 + fr;
  if (seg == 0) {
#pragma unroll
    for (int ni = 0; ni < 4; ++ni) {
      const int cgl = nbase + ni * 16;
      const float bb = bq[cgl];
      const int hh = cgl >> 6, d = cgl & 63;
#pragma unroll
      for (int mi = 0; mi < 8; ++mi) {
        const int m = m0 + wm * 128 + mi * 16 + g4;
        const int bi = m >> 11, t = m & 2047;
        u16* dst = &Qo[(((size_t)bi * HEADS + hh) * TT + t) * DH + d];
#pragma unroll
        for (int j = 0; j < 4; ++j)
          dst[(size_t)j * DH] = f2b((acc[mi][ni][j] + bb) * qs);
      }
    }
  } else if (seg == 1) {
#pragma unroll
    for (int ni = 0; ni < 4; ++ni) {
      const int cgl = nbase + ni * 16;
      const float bb = bk[cgl];
      const int hh = cgl >> 6, d = cgl & 63;
#pragma unroll
      for (int mi = 0; mi < 8; ++mi) {
        const int m = m0 + wm * 128 + mi * 16 + g4;
        const int bi = m >> 11, t = m & 2047;
        u16* dst = &Ko[(((size_t)bi * HEADS + hh) * TT + t) * DH + d];
#pragma unroll
        for (int j = 0; j < 4; ++j)
          dst[(size_t)j * DH] = f2b(acc[mi][ni][j] + bb);
      }
    }
  } else {
#pragma unroll
    for (int ni = 0; ni < 4; ++ni) {
      const int cgl = nbase + ni * 16;
      const float bb = bv[cgl];
      const int hh = cgl >> 6, d = cgl & 63;
#pragma unroll
      for (int mi = 0; mi < 8; ++mi) {
        const int t0 = (m0 + wm * 128 + mi * 16 + g4) & 2047;
        const int bi = (m0 + wm * 128 + mi * 16 + g4) >> 11;
        const int w64 = t0 & 63;
        const int pos = (t0 & ~63) | (((w64 >> 5) & 1) << 5) | (((w64 >> 2) & 3) << 3) |
                        (((w64 >> 4) & 1) << 2);
        ushort4 o;
        o.x = f2b(acc[mi][ni][0] + bb);
        o.y = f2b(acc[mi][ni][1] + bb);
        o.z = f2b(acc[mi][ni][2] + bb);
        o.w = f2b(acc[mi][ni][3] + bb);
        *(ushort4*)&Vto[(((size_t)bi * HEADS + hh) * DH + d) * TT + pos] = o;
      }
    }
  }
#undef STAGE_Ah
#undef STAGE_Bh
#undef READ_P1
#undef READ_P2
#undef MFMA_P1
#undef MFMA_P2
#undef STEP
#undef BARQ
#undef WAIT4
#undef WAIT0
}

// ---------------- O-projection GEMM (unchanged from round 11) ----------------
#define SLOT_OA (256 * 32)
#define SLOT_OB (128 * 32)
#define SLOT_OE (SLOT_OA + SLOT_OB)

__global__ __launch_bounds__(512, 2) void gemm_out8(const u16* __restrict__ A,
                                                    const u16* __restrict__ Bw,
                                                    const float* __restrict__ bias,
                                                    float* __restrict__ outp) {
  __shared__ u16 lds[4 * SLOT_OE];  // 96 KB
  const int tid = threadIdx.x, lane = tid & 63, wave = tid >> 6;
  const int fr = lane & 15, g = lane >> 4;
  const int wm = wave >> 1, wn = wave & 1;

  const int bx = blockIdx.x >> 5, by = blockIdx.x & 31;
  const int m0 = by * 256, n0 = bx * 128;

  const int srow = tid >> 2;
  const int schunk = (tid & 3) ^ ((tid >> 3) & 3);
  const u16* gA0 = A + (size_t)(m0 + srow) * DM + schunk * 8;
  const u16* gA1 = gA0 + (size_t)128 * DM;
  const u16* gB0 = Bw + (size_t)(n0 + srow) * DM + schunk * 8;
  const int dA0 = wave * 512;
  const int dA1 = 4096 + wave * 512;
  const int dB0 = SLOT_OA + wave * 512;

#define STAGEO(slot, kt) {                                   \
    u16* ls = &lds[(slot) * SLOT_OE];                        \
    const int ke = (kt) * 32;                                \
    gload_lds16(gA0 + ke, ls + dA0);                         \
    gload_lds16(gA1 + ke, ls + dA1);                         \
    gload_lds16(gB0 + ke, ls + dB0); }

  const int rchunk = (g ^ ((fr >> 1) & 3)) * 8;
  const int offA = (wm * 64 + fr) * 32 + rchunk;
  const int offB = SLOT_OA + (wn * 64 + fr) * 32 + rchunk;

  f32x4 acc[4][4];
#pragma unroll
  for (int mi = 0; mi < 4; ++mi)
#pragma unroll
    for (int ni = 0; ni < 4; ++ni) acc[mi][ni] = (f32x4){0.f, 0.f, 0.f, 0.f};

  bf16x8 afA[4], bfA[4], afB[4], bfB[4];

#define READO(AFv, BFv, kt) {                                \
    const u16* sl = &lds[((kt) & 3) * SLOT_OE];              \
    _Pragma("unroll")                                        \
    for (int mi = 0; mi < 4; ++mi)                           \
      AFv[mi] = *(const bf16x8*)&sl[offA + mi * 512];        \
    _Pragma("unroll")                                        \
    for (int ni = 0; ni < 4; ++ni)                           \
      BFv[ni] = *(const bf16x8*)&sl[offB + ni * 512]; }

#define MFMAO(AFv, BFv) {                                    \
    __builtin_amdgcn_s_setprio(1);                           \
    _Pragma("unroll")                                        \
    for (int mi = 0; mi < 4; ++mi)                           \
      _Pragma("unroll")                                      \
      for (int ni = 0; ni < 4; ++ni)                         \
        acc[mi][ni] = __builtin_amdgcn_mfma_f32_16x16x32_bf16(AFv[mi], BFv[ni], acc[mi][ni], 0, 0, 0); \
    __builtin_amdgcn_s_setprio(0); }

#define OW3 asm volatile("s_waitcnt vmcnt(3)" ::: "memory"); \
            asm volatile("s_barrier" ::: "memory");
#define OW0 asm volatile("s_waitcnt vmcnt(0)" ::: "memory"); \
            asm volatile("s_barrier" ::: "memory");

  STAGEO(0, 0)
  STAGEO(1, 1)
  STAGEO(2, 2)
  asm volatile("s_waitcnt vmcnt(6)" ::: "memory");
  asm volatile("s_barrier" ::: "memory");
  READO(afA, bfA, 0)

  for (int kt = 0; kt < 28; kt += 2) {
    OW3
    READO(afB, bfB, kt + 1)
    MFMAO(afA, bfA)
    STAGEO((kt + 3) & 3, kt + 3)
    OW3
    READO(afA, bfA, kt + 2)
    MFMAO(afB, bfB)
    STAGEO((kt + 4) & 3, kt + 4)
  }
  OW3
  READO(afB, bfB, 29)
  MFMAO(afA, bfA)
  STAGEO(3, 31)
  OW3
  READO(afA, bfA, 30)
  MFMAO(afB, bfB)
  OW0
  READO(afB, bfB, 31)
  MFMAO(afA, bfA)
  MFMAO(afB, bfB)

  const int g4 = g * 4;
#pragma unroll
  for (int mi = 0; mi < 4; ++mi) {
    const int rg = m0 + wm * 64 + mi * 16 + g4;
#pragma unroll
    for (int ni = 0; ni < 4; ++ni) {
      const int cg = n0 + wn * 64 + ni * 16 + fr;
      const float bb = bias[cg];
#pragma unroll
      for (int j = 0; j < 4; ++j)
        outp[(size_t)(rg + j) * DM + cg] = acc[mi][ni][j] + bb;
    }
  }
#undef STAGEO
#undef READO
#undef MFMAO
#undef OW3
#undef OW0
}

// ---------------- flash attention, causal: single q-tile blocks, LPT order ----
// 2048 blocks.  Decode keeps all 32 qt-blocks of a (b,h) on ONE XCD
// (o % 8 == xcd invariant) and emits qt DESCENDING within each XCD so the
// heaviest blocks dispatch first (LPT packing of the causal 1..32-tile spread).
// Inner loop is the round-10/11 proven body: XOR-swizzled [64][64] LDS,
// S^T = mfma(K,Q), P-in-register via cvt_pk with sigma-permuted V columns.
__global__ __launch_bounds__(256) void attn_fwd(const u16* __restrict__ Q,
                                                const u16* __restrict__ K,
                                                const u16* __restrict__ Vt,
                                                u16* __restrict__ O) {
  const int o_ = blockIdx.x;
  const int xcd = o_ & 7, j = o_ >> 3;     // j in [0,256)
  const int gi = j & 7;                    // group within XCD
  const int qt = 31 - (j >> 3);            // qt descending as j increases
  const int gidx = xcd * 8 + gi;           // (b,h) group 0..63
  const int b = gidx >> 4, h = gidx & 15;
  const int tid = threadIdx.x, lane = tid & 63, wave = tid >> 6;
  __shared__ u16 Ks[64 * 64];
  __shared__ u16 Vs[64 * 64];

  const size_t bh = ((size_t)b * HEADS + h) * TT;
  const size_t vbse = ((size_t)b * HEADS + h) * DH;
  const int fr = lane & 15, g = lane >> 4;
  const int sr = tid >> 2;
  const int sc0 = tid & 3;

  const int sw1 = (sc0 ^ (sr & 7)) * 8;
  const int sw2 = ((sc0 + 4) ^ (sr & 7)) * 8;
  const int sgc = sc0 * 8;
  const int rk0 = (g ^ (fr & 7)) * 8;
  const int rk1 = ((4 + g) ^ (fr & 7)) * 8;
  const int k8 = g * 8;

  const int q0 = qt * 64;
  const int qrow = q0 + wave * 16 + fr;      // this lane's q-row
  const bf16x8 qf0 = *(const bf16x8*)&Q[(bh + qrow) * DH + k8];
  const bf16x8 qf1 = *(const bf16x8*)&Q[(bh + qrow) * DH + 32 + k8];

  float lsum = 0.f;
  f32x4 oacc[4];
#pragma unroll
  for (int c = 0; c < 4; ++c) oacc[c] = (f32x4){0.f, 0.f, 0.f, 0.f};

  for (int kvb = 0; kvb <= qt; ++kvb) {
    const int kv0 = kvb * 64;
    {
      const u16* kg = &K[(bh + kv0 + sr) * DH + sgc];
      u16x8 ka = *(const u16x8*)kg;
      u16x8 kc = *(const u16x8*)(kg + 32);
      const u16* vg = &Vt[(vbse + sr) * TT + kv0 + sgc];
      u16x8 va = *(const u16x8*)vg;
      u16x8 vc = *(const u16x8*)(vg + 32);
      *(u16x8*)&Ks[sr * 64 + sw1] = ka;
      *(u16x8*)&Ks[sr * 64 + sw2] = kc;
      *(u16x8*)&Vs[sr * 64 + sw1] = va;
      *(u16x8*)&Vs[sr * 64 + sw2] = vc;
    }
    __syncthreads();

    // S^T = K Q  (log2 domain; scale folded into Q)
    f32x4 s[4];
    __builtin_amdgcn_s_setprio(1);
#pragma unroll
    for (int c = 0; c < 4; ++c) {
      bf16x8 kb0 = *(const bf16x8*)&Ks[(c * 16 + fr) * 64 + rk0];
      bf16x8 kb1 = *(const bf16x8*)&Ks[(c * 16 + fr) * 64 + rk1];
      f32x4 t = (f32x4){0.f, 0.f, 0.f, 0.f};
      t = __builtin_amdgcn_mfma_f32_16x16x32_bf16(kb0, qf0, t, 0, 0, 0);
      t = __builtin_amdgcn_mfma_f32_16x16x32_bf16(kb1, qf1, t, 0, 0, 0);
      s[c] = t;
    }
    __builtin_amdgcn_s_setprio(0);

    if (kvb == qt) {  // diagonal tile: causal mask (in-lane, row = qrow)
#pragma unroll
      for (int c = 0; c < 4; ++c) {
        const int colg = kv0 + c * 16 + 4 * g;
#pragma unroll
        for (int r = 0; r < 4; ++r)
          if (colg + r > qrow) s[c][r] = -1e30f;
      }
    }

    // p = exp2(s), packed in-register; row-sum
    float rs = 0.f;
    uint32_t pk[8];
#pragma unroll
    for (int c = 0; c < 4; ++c) {
      float p0 = __builtin_amdgcn_exp2f(s[c][0]);
      float p1 = __builtin_amdgcn_exp2f(s[c][1]);
      float p2 = __builtin_amdgcn_exp2f(s[c][2]);
      float p3 = __builtin_amdgcn_exp2f(s[c][3]);
      rs += (p0 + p1) + (p2 + p3);
      pk[2 * c] = cvtpk(p0, p1);
      pk[2 * c + 1] = cvtpk(p2, p3);
    }
    rs += __shfl_xor(rs, 16);
    rs += __shfl_xor(rs, 32);
    lsum += rs;

    const bf16x8 pa0 = __builtin_bit_cast(bf16x8, (u32x4){pk[0], pk[1], pk[2], pk[3]});
    const bf16x8 pa1 = __builtin_bit_cast(bf16x8, (u32x4){pk[4], pk[5], pk[6], pk[7]});

    // O^T += V^T P^T   (V columns pre-permuted to match pa slots)
    __builtin_amdgcn_s_setprio(1);
#pragma unroll
    for (int c = 0; c < 4; ++c) {
      bf16x8 vb0 = *(const bf16x8*)&Vs[(c * 16 + fr) * 64 + rk0];
      bf16x8 vb1 = *(const bf16x8*)&Vs[(c * 16 + fr) * 64 + rk1];
      oacc[c] = __builtin_amdgcn_mfma_f32_16x16x32_bf16(vb0, pa0, oacc[c], 0, 0, 0);
      oacc[c] = __builtin_amdgcn_mfma_f32_16x16x32_bf16(vb1, pa1, oacc[c], 0, 0, 0);
    }
    __builtin_amdgcn_s_setprio(0);
    __syncthreads();
  }

  // epilogue: lane owns O[qrow][d = c*16 + 4g + r] -> packed ushort4 stores
  const float inv = 1.f / lsum;
#pragma unroll
  for (int c = 0; c < 4; ++c) {
    ushort4 o;
    o.x = f2b(oacc[c][0] * inv);
    o.y = f2b(oacc[c][1] * inv);
    o.z = f2b(oacc[c][2] * inv);
    o.w = f2b(oacc[c][3] * inv);
    *(ushort4*)&O[((size_t)b * TT + qrow) * DM + h * DH + c * 16 + 4 * g] = o;
  }
}

extern "C" void kernel_launch(void* const* d_in, const int* in_sizes, int n_in,
                              void* d_out, int out_size, void* d_ws, size_t ws_size,
                              hipStream_t stream) {
  const float* x  = (const float*)d_in[0];
  const float* Wq = (const float*)d_in[1];
  const float* bq = (const float*)d_in[2];
  const float* Wk = (const float*)d_in[3];
  const float* bk = (const float*)d_in[4];
  const float* Wv = (const float*)d_in[5];
  const float* bv = (const float*)d_in[6];
  const float* Wo = (const float*)d_in[7];
  const float* bo = (const float*)d_in[8];

  char* w = (char*)d_ws;
  u16* xb    = (u16*)w; w += (size_t)MTOT * DM * 2;
  u16* Wqkvb = (u16*)w; w += (size_t)3 * DM * DM * 2;
  u16* Wob   = (u16*)w; w += (size_t)DM * DM * 2;
  u16* Qb    = (u16*)w; w += (size_t)MTOT * DM * 2;
  u16* Kb    = (u16*)w; w += (size_t)MTOT * DM * 2;
  u16* Vtb   = (u16*)w; w += (size_t)MTOT * DM * 2;
  u16* AOb   = (u16*)w; w += (size_t)MTOT * DM * 2;

  cast_all<<<(NX + 4 * NW) / 256, 256, 0, stream>>>(x, Wq, Wk, Wv, Wo, xb, Wqkvb, Wob);

  const float qs = 0.125f * 1.44269504f;  // 1/sqrt(64) * log2(e), folded into Q
  gemm_qkv8<<<384, 512, 0, stream>>>(xb, Wqkvb, bq, bk, bv, Qb, Kb, Vtb, qs);

  attn_fwd<<<2048, 256, 0, stream>>>(Qb, Kb, Vtb, AOb);

  gemm_out8<<<256, 512, 0, stream>>>(AOb, Wob, bo, (float*)d_out);
}

// Round 14
// 155.535 us; speedup vs baseline: 1.1216x; 1.0285x over previous
//
#include <hip/hip_runtime.h>
#include <stdint.h>

#define DM 1024
#define HEADS 16
#define DH 64
#define BQ 4
#define TT 2048
#define MTOT (BQ*TT)  // 8192
#define NQT (TT/64)   // 32 q-tiles per (b,h)

typedef __attribute__((ext_vector_type(8))) __bf16 bf16x8;
typedef __attribute__((ext_vector_type(4))) float f32x4;
typedef __attribute__((ext_vector_type(4))) uint32_t u32x4;
typedef unsigned short u16;
typedef __attribute__((ext_vector_type(8))) unsigned short u16x8;

__device__ __forceinline__ u16 f2b(float f) {
  uint32_t u = __builtin_bit_cast(uint32_t, f);
  u = (u + 0x7fffu + ((u >> 16) & 1u)) >> 16;
  return (u16)u;
}

__device__ __forceinline__ uint32_t cvtpk(float lo, float hi) {
  uint32_t r;
  asm("v_cvt_pk_bf16_f32 %0, %1, %2" : "=v"(r) : "v"(lo), "v"(hi));
  return r;
}

__device__ __forceinline__ void gload_lds16(const u16* g, u16* l) {
  __builtin_amdgcn_global_load_lds(
      (const __attribute__((address_space(1))) void*)g,
      (__attribute__((address_space(3))) void*)l, 16, 0, 0);
}

// ---------------- fused cast: x, Wq|Wk|Wv (contiguous), Wo -> bf16 ----------------
#define NX (MTOT * DM / 4)   // float4s in x
#define NW (DM * DM / 4)     // float4s per weight matrix
__global__ __launch_bounds__(256) void cast_all(const float* __restrict__ x,
                                                const float* __restrict__ Wq,
                                                const float* __restrict__ Wk,
                                                const float* __restrict__ Wv,
                                                const float* __restrict__ Wo,
                                                u16* __restrict__ xb,
                                                u16* __restrict__ wqkvb,
                                                u16* __restrict__ wob) {
  int i = blockIdx.x * 256 + threadIdx.x;
  const float* src; u16* dst;
  if (i < NX)               { src = x;  dst = xb; }
  else if (i < NX + NW)     { src = Wq; dst = wqkvb;          i -= NX; }
  else if (i < NX + 2 * NW) { src = Wk; dst = wqkvb + 4 * NW; i -= NX + NW; }
  else if (i < NX + 3 * NW) { src = Wv; dst = wqkvb + 8 * NW; i -= NX + 2 * NW; }
  else                      { src = Wo; dst = wob;            i -= NX + 3 * NW; }
  float4 v = ((const float4*)src)[i];
  ushort4 o;
  o.x = f2b(v.x); o.y = f2b(v.y); o.z = f2b(v.z); o.w = f2b(v.w);
  ((ushort4*)dst)[i] = o;
}

// ---------------- fused QKV GEMM on the out8 template: BM=256 BN=128 BK=32 ----
// 768 blocks = EXACTLY 3 full block-rounds (no tail; old 384-grid was 1.5
// rounds = 50% idle).  4-slot ring (24KB/slot, 96KB), 3 loads/slot, depth-3
// prefetch, vmcnt(3) steady.  8 waves 4Mx2N, wave tile 64x64.  XCD swizzle
// (768 % 8 == 0).  Epilogue: seg 0 Q (scaled), 1 K, 2 V^T sigma-permuted.
#define SLOT_QA (256 * 32)
#define SLOT_QB (128 * 32)
#define SLOT_QE (SLOT_QA + SLOT_QB)  // 12288 elems (24KB)

__global__ __launch_bounds__(512, 2) void gemm_qkv8(const u16* __restrict__ A,
                                                    const u16* __restrict__ W,
                                                    const float* __restrict__ bq,
                                                    const float* __restrict__ bk,
                                                    const float* __restrict__ bv,
                                                    u16* __restrict__ Qo,
                                                    u16* __restrict__ Ko,
                                                    u16* __restrict__ Vto,
                                                    float qs) {
  __shared__ u16 lds[4 * SLOT_QE];  // 96 KB
  const int tid = threadIdx.x, lane = tid & 63, wave = tid >> 6;
  const int fr = lane & 15, g = lane >> 4;
  const int wm = wave >> 1, wn = wave & 1;

  // XCD swizzle: 768 = 8 * 96
  int bid = blockIdx.x;
  bid = (bid & 7) * 96 + (bid >> 3);
  const int by = bid / 24, bx = bid % 24;       // by: m-tile(32), bx: n-tile(24)
  const int m0 = by * 256, n0 = bx * 128;

  const int srow = tid >> 2;                    // 0..127
  const int schunk = (tid & 3) ^ ((tid >> 3) & 3);
  const u16* gA0 = A + (size_t)(m0 + srow) * DM + schunk * 8;
  const u16* gA1 = gA0 + (size_t)128 * DM;
  const u16* gB0 = W + (size_t)(n0 + srow) * DM + schunk * 8;
  const int dA0 = wave * 512;
  const int dA1 = 4096 + wave * 512;
  const int dB0 = SLOT_QA + wave * 512;

#define STAGEQ(slot, kt) {                                   \
    u16* ls = &lds[(slot) * SLOT_QE];                        \
    const int ke = (kt) * 32;                                \
    gload_lds16(gA0 + ke, ls + dA0);                         \
    gload_lds16(gA1 + ke, ls + dA1);                         \
    gload_lds16(gB0 + ke, ls + dB0); }

  const int rchunk = (g ^ ((fr >> 1) & 3)) * 8;
  const int offA = (wm * 64 + fr) * 32 + rchunk;
  const int offB = SLOT_QA + (wn * 64 + fr) * 32 + rchunk;

  f32x4 acc[4][4];
#pragma unroll
  for (int mi = 0; mi < 4; ++mi)
#pragma unroll
    for (int ni = 0; ni < 4; ++ni) acc[mi][ni] = (f32x4){0.f, 0.f, 0.f, 0.f};

  bf16x8 afA[4], bfA[4], afB[4], bfB[4];

#define READQ(AFv, BFv, kt) {                                \
    const u16* sl = &lds[((kt) & 3) * SLOT_QE];              \
    _Pragma("unroll")                                        \
    for (int mi = 0; mi < 4; ++mi)                           \
      AFv[mi] = *(const bf16x8*)&sl[offA + mi * 512];        \
    _Pragma("unroll")                                        \
    for (int ni = 0; ni < 4; ++ni)                           \
      BFv[ni] = *(const bf16x8*)&sl[offB + ni * 512]; }

#define MFMAQ(AFv, BFv) {                                    \
    __builtin_amdgcn_s_setprio(1);                           \
    _Pragma("unroll")                                        \
    for (int mi = 0; mi < 4; ++mi)                           \
      _Pragma("unroll")                                      \
      for (int ni = 0; ni < 4; ++ni)                         \
        acc[mi][ni] = __builtin_amdgcn_mfma_f32_16x16x32_bf16(AFv[mi], BFv[ni], acc[mi][ni], 0, 0, 0); \
    __builtin_amdgcn_s_setprio(0); }

#define QW3 asm volatile("s_waitcnt vmcnt(3)" ::: "memory"); \
            asm volatile("s_barrier" ::: "memory");
#define QW0 asm volatile("s_waitcnt vmcnt(0)" ::: "memory"); \
            asm volatile("s_barrier" ::: "memory");

  STAGEQ(0, 0)
  STAGEQ(1, 1)
  STAGEQ(2, 2)
  asm volatile("s_waitcnt vmcnt(6)" ::: "memory");
  asm volatile("s_barrier" ::: "memory");
  READQ(afA, bfA, 0)

  for (int kt = 0; kt < 28; kt += 2) {
    QW3
    READQ(afB, bfB, kt + 1)
    MFMAQ(afA, bfA)
    STAGEQ((kt + 3) & 3, kt + 3)
    QW3
    READQ(afA, bfA, kt + 2)
    MFMAQ(afB, bfB)
    STAGEQ((kt + 4) & 3, kt + 4)
  }
  QW3
  READQ(afB, bfB, 29)
  MFMAQ(afA, bfA)          // kt=28
  STAGEQ(3, 31)
  QW3
  READQ(afA, bfA, 30)
  MFMAQ(afB, bfB)          // kt=29
  QW0
  READQ(afB, bfB, 31)
  MFMAQ(afA, bfA)          // kt=30
  MFMAQ(afB, bfB)          // kt=31

  // epilogue: m = m0 + wm*64 + mi*16 + g*4 + j ; n = n0 + wn*64 + ni*16 + fr
  const int g4 = g * 4;
  const int seg = n0 >> 10;
  const int nbase = (n0 & 1023) + wn * 64 + fr;
  if (seg == 0) {
#pragma unroll
    for (int ni = 0; ni < 4; ++ni) {
      const int cgl = nbase + ni * 16;
      const float bb = bq[cgl];
      const int hh = cgl >> 6, d = cgl & 63;
#pragma unroll
      for (int mi = 0; mi < 4; ++mi) {
        const int m = m0 + wm * 64 + mi * 16 + g4;
        const int bi = m >> 11, t = m & 2047;
        u16* dst = &Qo[(((size_t)bi * HEADS + hh) * TT + t) * DH + d];
#pragma unroll
        for (int j = 0; j < 4; ++j)
          dst[(size_t)j * DH] = f2b((acc[mi][ni][j] + bb) * qs);
      }
    }
  } else if (seg == 1) {
#pragma unroll
    for (int ni = 0; ni < 4; ++ni) {
      const int cgl = nbase + ni * 16;
      const float bb = bk[cgl];
      const int hh = cgl >> 6, d = cgl & 63;
#pragma unroll
      for (int mi = 0; mi < 4; ++mi) {
        const int m = m0 + wm * 64 + mi * 16 + g4;
        const int bi = m >> 11, t = m & 2047;
        u16* dst = &Ko[(((size_t)bi * HEADS + hh) * TT + t) * DH + d];
#pragma unroll
        for (int j = 0; j < 4; ++j)
          dst[(size_t)j * DH] = f2b(acc[mi][ni][j] + bb);
      }
    }
  } else {
#pragma unroll
    for (int ni = 0; ni < 4; ++ni) {
      const int cgl = nbase + ni * 16;
      const float bb = bv[cgl];
      const int hh = cgl >> 6, d = cgl & 63;
#pragma unroll
      for (int mi = 0; mi < 4; ++mi) {
        const int m = m0 + wm * 64 + mi * 16 + g4;
        const int t0 = m & 2047, bi = m >> 11;
        const int w64 = t0 & 63;
        const int pos = (t0 & ~63) | (((w64 >> 5) & 1) << 5) | (((w64 >> 2) & 3) << 3) |
                        (((w64 >> 4) & 1) << 2);
        ushort4 o;
        o.x = f2b(acc[mi][ni][0] + bb);
        o.y = f2b(acc[mi][ni][1] + bb);
        o.z = f2b(acc[mi][ni][2] + bb);
        o.w = f2b(acc[mi][ni][3] + bb);
        *(ushort4*)&Vto[(((size_t)bi * HEADS + hh) * DH + d) * TT + pos] = o;
      }
    }
  }
#undef STAGEQ
#undef READQ
#undef MFMAQ
#undef QW3
#undef QW0
}

// ---------------- O-projection GEMM (unchanged from round 11) ----------------
#define SLOT_OA (256 * 32)
#define SLOT_OB (128 * 32)
#define SLOT_OE (SLOT_OA + SLOT_OB)

__global__ __launch_bounds__(512, 2) void gemm_out8(const u16* __restrict__ A,
                                                    const u16* __restrict__ Bw,
                                                    const float* __restrict__ bias,
                                                    float* __restrict__ outp) {
  __shared__ u16 lds[4 * SLOT_OE];  // 96 KB
  const int tid = threadIdx.x, lane = tid & 63, wave = tid >> 6;
  const int fr = lane & 15, g = lane >> 4;
  const int wm = wave >> 1, wn = wave & 1;

  const int bx = blockIdx.x >> 5, by = blockIdx.x & 31;
  const int m0 = by * 256, n0 = bx * 128;

  const int srow = tid >> 2;
  const int schunk = (tid & 3) ^ ((tid >> 3) & 3);
  const u16* gA0 = A + (size_t)(m0 + srow) * DM + schunk * 8;
  const u16* gA1 = gA0 + (size_t)128 * DM;
  const u16* gB0 = Bw + (size_t)(n0 + srow) * DM + schunk * 8;
  const int dA0 = wave * 512;
  const int dA1 = 4096 + wave * 512;
  const int dB0 = SLOT_OA + wave * 512;

#define STAGEO(slot, kt) {                                   \
    u16* ls = &lds[(slot) * SLOT_OE];                        \
    const int ke = (kt) * 32;                                \
    gload_lds16(gA0 + ke, ls + dA0);                         \
    gload_lds16(gA1 + ke, ls + dA1);                         \
    gload_lds16(gB0 + ke, ls + dB0); }

  const int rchunk = (g ^ ((fr >> 1) & 3)) * 8;
  const int offA = (wm * 64 + fr) * 32 + rchunk;
  const int offB = SLOT_OA + (wn * 64 + fr) * 32 + rchunk;

  f32x4 acc[4][4];
#pragma unroll
  for (int mi = 0; mi < 4; ++mi)
#pragma unroll
    for (int ni = 0; ni < 4; ++ni) acc[mi][ni] = (f32x4){0.f, 0.f, 0.f, 0.f};

  bf16x8 afA[4], bfA[4], afB[4], bfB[4];

#define READO(AFv, BFv, kt) {                                \
    const u16* sl = &lds[((kt) & 3) * SLOT_OE];              \
    _Pragma("unroll")                                        \
    for (int mi = 0; mi < 4; ++mi)                           \
      AFv[mi] = *(const bf16x8*)&sl[offA + mi * 512];        \
    _Pragma("unroll")                                        \
    for (int ni = 0; ni < 4; ++ni)                           \
      BFv[ni] = *(const bf16x8*)&sl[offB + ni * 512]; }

#define MFMAO(AFv, BFv) {                                    \
    __builtin_amdgcn_s_setprio(1);                           \
    _Pragma("unroll")                                        \
    for (int mi = 0; mi < 4; ++mi)                           \
      _Pragma("unroll")                                      \
      for (int ni = 0; ni < 4; ++ni)                         \
        acc[mi][ni] = __builtin_amdgcn_mfma_f32_16x16x32_bf16(AFv[mi], BFv[ni], acc[mi][ni], 0, 0, 0); \
    __builtin_amdgcn_s_setprio(0); }

#define OW3 asm volatile("s_waitcnt vmcnt(3)" ::: "memory"); \
            asm volatile("s_barrier" ::: "memory");
#define OW0 asm volatile("s_waitcnt vmcnt(0)" ::: "memory"); \
            asm volatile("s_barrier" ::: "memory");

  STAGEO(0, 0)
  STAGEO(1, 1)
  STAGEO(2, 2)
  asm volatile("s_waitcnt vmcnt(6)" ::: "memory");
  asm volatile("s_barrier" ::: "memory");
  READO(afA, bfA, 0)

  for (int kt = 0; kt < 28; kt += 2) {
    OW3
    READO(afB, bfB, kt + 1)
    MFMAO(afA, bfA)
    STAGEO((kt + 3) & 3, kt + 3)
    OW3
    READO(afA, bfA, kt + 2)
    MFMAO(afB, bfB)
    STAGEO((kt + 4) & 3, kt + 4)
  }
  OW3
  READO(afB, bfB, 29)
  MFMAO(afA, bfA)
  STAGEO(3, 31)
  OW3
  READO(afA, bfA, 30)
  MFMAO(afB, bfB)
  OW0
  READO(afB, bfB, 31)
  MFMAO(afA, bfA)
  MFMAO(afB, bfB)

  const int g4 = g * 4;
#pragma unroll
  for (int mi = 0; mi < 4; ++mi) {
    const int rg = m0 + wm * 64 + mi * 16 + g4;
#pragma unroll
    for (int ni = 0; ni < 4; ++ni) {
      const int cg = n0 + wn * 64 + ni * 16 + fr;
      const float bb = bias[cg];
#pragma unroll
      for (int j = 0; j < 4; ++j)
        outp[(size_t)(rg + j) * DM + cg] = acc[mi][ni][j] + bb;
    }
  }
#undef STAGEO
#undef READO
#undef MFMAO
#undef OW3
#undef OW0
}

// ---------------- flash attention, causal, QBLK=128 (2 q-groups/wave) ----------
// 1024 blocks: xcd = o&7 keeps all blocks of a (b,h) on one XCD; qt128
// DESCENDING within each XCD (LPT).  Each wave owns 32 q-rows: group L at
// q0+w*16+fr and group H at q0+64+w*16+fr.  Each K/V LDS fragment is read
// ONCE and feeds both groups' MFMAs -> LDS read traffic per q-row halves.
// Masks (block-uniform branch kvb >= qtL): L by qrowL, H by qrowH; at
// kvb==qtH group L masks to all-zero (P=0 contributes nothing — correct);
// at kvb==qtL group H's mask is vacuous (cols < q0+64 <= qrowH).
__global__ __launch_bounds__(256) void attn_fwd(const u16* __restrict__ Q,
                                                const u16* __restrict__ K,
                                                const u16* __restrict__ Vt,
                                                u16* __restrict__ O) {
  const int o_ = blockIdx.x;
  const int xcd = o_ & 7, j = o_ >> 3;     // j in [0,128)
  const int gi = j & 7;                    // group within XCD
  const int qt128 = 15 - (j >> 3);         // descending (LPT)
  const int gidx = xcd * 8 + gi;           // (b,h) group 0..63
  const int b = gidx >> 4, h = gidx & 15;
  const int tid = threadIdx.x, lane = tid & 63, wave = tid >> 6;
  __shared__ u16 Ks[64 * 64];
  __shared__ u16 Vs[64 * 64];

  const size_t bh = ((size_t)b * HEADS + h) * TT;
  const size_t vbse = ((size_t)b * HEADS + h) * DH;
  const int fr = lane & 15, g = lane >> 4;
  const int sr = tid >> 2;
  const int sc0 = tid & 3;

  const int sw1 = (sc0 ^ (sr & 7)) * 8;
  const int sw2 = ((sc0 + 4) ^ (sr & 7)) * 8;
  const int sgc = sc0 * 8;
  const int rk0 = (g ^ (fr & 7)) * 8;
  const int rk1 = ((4 + g) ^ (fr & 7)) * 8;
  const int k8 = g * 8;

  const int q0 = qt128 * 128;
  const int qtL = 2 * qt128, qtH = qtL + 1;
  const int qrowL = q0 + wave * 16 + fr;
  const int qrowH = q0 + 64 + wave * 16 + fr;
  const bf16x8 qfL0 = *(const bf16x8*)&Q[(bh + qrowL) * DH + k8];
  const bf16x8 qfL1 = *(const bf16x8*)&Q[(bh + qrowL) * DH + 32 + k8];
  const bf16x8 qfH0 = *(const bf16x8*)&Q[(bh + qrowH) * DH + k8];
  const bf16x8 qfH1 = *(const bf16x8*)&Q[(bh + qrowH) * DH + 32 + k8];

  float lsumL = 0.f, lsumH = 0.f;
  f32x4 oaccL[4], oaccH[4];
#pragma unroll
  for (int c = 0; c < 4; ++c) {
    oaccL[c] = (f32x4){0.f, 0.f, 0.f, 0.f};
    oaccH[c] = (f32x4){0.f, 0.f, 0.f, 0.f};
  }

  for (int kvb = 0; kvb <= qtH; ++kvb) {
    const int kv0 = kvb * 64;
    {
      const u16* kg = &K[(bh + kv0 + sr) * DH + sgc];
      u16x8 ka = *(const u16x8*)kg;
      u16x8 kc = *(const u16x8*)(kg + 32);
      const u16* vg = &Vt[(vbse + sr) * TT + kv0 + sgc];
      u16x8 va = *(const u16x8*)vg;
      u16x8 vc = *(const u16x8*)(vg + 32);
      *(u16x8*)&Ks[sr * 64 + sw1] = ka;
      *(u16x8*)&Ks[sr * 64 + sw2] = kc;
      *(u16x8*)&Vs[sr * 64 + sw1] = va;
      *(u16x8*)&Vs[sr * 64 + sw2] = vc;
    }
    __syncthreads();

    // S^T = K Q for both q-groups; K fragments read ONCE
    f32x4 sL[4], sH[4];
    __builtin_amdgcn_s_setprio(1);
#pragma unroll
    for (int c = 0; c < 4; ++c) {
      bf16x8 kb0 = *(const bf16x8*)&Ks[(c * 16 + fr) * 64 + rk0];
      bf16x8 kb1 = *(const bf16x8*)&Ks[(c * 16 + fr) * 64 + rk1];
      f32x4 tL = (f32x4){0.f, 0.f, 0.f, 0.f};
      tL = __builtin_amdgcn_mfma_f32_16x16x32_bf16(kb0, qfL0, tL, 0, 0, 0);
      tL = __builtin_amdgcn_mfma_f32_16x16x32_bf16(kb1, qfL1, tL, 0, 0, 0);
      sL[c] = tL;
      f32x4 tH = (f32x4){0.f, 0.f, 0.f, 0.f};
      tH = __builtin_amdgcn_mfma_f32_16x16x32_bf16(kb0, qfH0, tH, 0, 0, 0);
      tH = __builtin_amdgcn_mfma_f32_16x16x32_bf16(kb1, qfH1, tH, 0, 0, 0);
      sH[c] = tH;
    }
    __builtin_amdgcn_s_setprio(0);

    if (kvb >= qtL) {  // diagonal band: mask both groups in-lane
#pragma unroll
      for (int c = 0; c < 4; ++c) {
        const int colg = kv0 + c * 16 + 4 * g;
#pragma unroll
        for (int r = 0; r < 4; ++r) {
          if (colg + r > qrowL) sL[c][r] = -1e30f;
          if (colg + r > qrowH) sH[c][r] = -1e30f;
        }
      }
    }

    // p = exp2(s), packed in-register; row-sums
    float rsL = 0.f, rsH = 0.f;
    uint32_t pkL[8], pkH[8];
#pragma unroll
    for (int c = 0; c < 4; ++c) {
      float l0 = __builtin_amdgcn_exp2f(sL[c][0]);
      float l1 = __builtin_amdgcn_exp2f(sL[c][1]);
      float l2 = __builtin_amdgcn_exp2f(sL[c][2]);
      float l3 = __builtin_amdgcn_exp2f(sL[c][3]);
      rsL += (l0 + l1) + (l2 + l3);
      pkL[2 * c] = cvtpk(l0, l1);
      pkL[2 * c + 1] = cvtpk(l2, l3);
      float h0 = __builtin_amdgcn_exp2f(sH[c][0]);
      float h1 = __builtin_amdgcn_exp2f(sH[c][1]);
      float h2 = __builtin_amdgcn_exp2f(sH[c][2]);
      float h3 = __builtin_amdgcn_exp2f(sH[c][3]);
      rsH += (h0 + h1) + (h2 + h3);
      pkH[2 * c] = cvtpk(h0, h1);
      pkH[2 * c + 1] = cvtpk(h2, h3);
    }
    rsL += __shfl_xor(rsL, 16);
    rsL += __shfl_xor(rsL, 32);
    lsumL += rsL;
    rsH += __shfl_xor(rsH, 16);
    rsH += __shfl_xor(rsH, 32);
    lsumH += rsH;

    const bf16x8 paL0 = __builtin_bit_cast(bf16x8, (u32x4){pkL[0], pkL[1], pkL[2], pkL[3]});
    const bf16x8 paL1 = __builtin_bit_cast(bf16x8, (u32x4){pkL[4], pkL[5], pkL[6], pkL[7]});
    const bf16x8 paH0 = __builtin_bit_cast(bf16x8, (u32x4){pkH[0], pkH[1], pkH[2], pkH[3]});
    const bf16x8 paH1 = __builtin_bit_cast(bf16x8, (u32x4){pkH[4], pkH[5], pkH[6], pkH[7]});

    // O^T += V^T P^T for both groups; V fragments read ONCE
    __builtin_amdgcn_s_setprio(1);
#pragma unroll
    for (int c = 0; c < 4; ++c) {
      bf16x8 vb0 = *(const bf16x8*)&Vs[(c * 16 + fr) * 64 + rk0];
      bf16x8 vb1 = *(const bf16x8*)&Vs[(c * 16 + fr) * 64 + rk1];
      oaccL[c] = __builtin_amdgcn_mfma_f32_16x16x32_bf16(vb0, paL0, oaccL[c], 0, 0, 0);
      oaccL[c] = __builtin_amdgcn_mfma_f32_16x16x32_bf16(vb1, paL1, oaccL[c], 0, 0, 0);
      oaccH[c] = __builtin_amdgcn_mfma_f32_16x16x32_bf16(vb0, paH0, oaccH[c], 0, 0, 0);
      oaccH[c] = __builtin_amdgcn_mfma_f32_16x16x32_bf16(vb1, paH1, oaccH[c], 0, 0, 0);
    }
    __builtin_amdgcn_s_setprio(0);
    __syncthreads();
  }

  // epilogues: lane owns O[qrow][d = c*16 + 4g + r]
  const float invL = 1.f / lsumL;
#pragma unroll
  for (int c = 0; c < 4; ++c) {
    ushort4 o;
    o.x = f2b(oaccL[c][0] * invL);
    o.y = f2b(oaccL[c][1] * invL);
    o.z = f2b(oaccL[c][2] * invL);
    o.w = f2b(oaccL[c][3] * invL);
    *(ushort4*)&O[((size_t)b * TT + qrowL) * DM + h * DH + c * 16 + 4 * g] = o;
  }
  const float invH = 1.f / lsumH;
#pragma unroll
  for (int c = 0; c < 4; ++c) {
    ushort4 o;
    o.x = f2b(oaccH[c][0] * invH);
    o.y = f2b(oaccH[c][1] * invH);
    o.z = f2b(oaccH[c][2] * invH);
    o.w = f2b(oaccH[c][3] * invH);
    *(ushort4*)&O[((size_t)b * TT + qrowH) * DM + h * DH + c * 16 + 4 * g] = o;
  }
}

extern "C" void kernel_launch(void* const* d_in, const int* in_sizes, int n_in,
                              void* d_out, int out_size, void* d_ws, size_t ws_size,
                              hipStream_t stream) {
  const float* x  = (const float*)d_in[0];
  const float* Wq = (const float*)d_in[1];
  const float* bq = (const float*)d_in[2];
  const float* Wk = (const float*)d_in[3];
  const float* bk = (const float*)d_in[4];
  const float* Wv = (const float*)d_in[5];
  const float* bv = (const float*)d_in[6];
  const float* Wo = (const float*)d_in[7];
  const float* bo = (const float*)d_in[8];

  char* w = (char*)d_ws;
  u16* xb    = (u16*)w; w += (size_t)MTOT * DM * 2;
  u16* Wqkvb = (u16*)w; w += (size_t)3 * DM * DM * 2;
  u16* Wob   = (u16*)w; w += (size_t)DM * DM * 2;
  u16* Qb    = (u16*)w; w += (size_t)MTOT * DM * 2;
  u16* Kb    = (u16*)w; w += (size_t)MTOT * DM * 2;
  u16* Vtb   = (u16*)w; w += (size_t)MTOT * DM * 2;
  u16* AOb   = (u16*)w; w += (size_t)MTOT * DM * 2;

  cast_all<<<(NX + 4 * NW) / 256, 256, 0, stream>>>(x, Wq, Wk, Wv, Wo, xb, Wqkvb, Wob);

  const float qs = 0.125f * 1.44269504f;  // 1/sqrt(64) * log2(e), folded into Q
  gemm_qkv8<<<768, 512, 0, stream>>>(xb, Wqkvb, bq, bk, bv, Qb, Kb, Vtb, qs);

  attn_fwd<<<1024, 256, 0, stream>>>(Qb, Kb, Vtb, AOb);

  gemm_out8<<<256, 512, 0, stream>>>(AOb, Wob, bo, (float*)d_out);
}